// Round 3
// baseline (449.812 us; speedup 1.0000x reference)
//
#include <hip/hip_runtime.h>

typedef __attribute__((ext_vector_type(8))) __bf16 bf16x8;
typedef __attribute__((ext_vector_type(4))) __bf16 bf16x4;
typedef __attribute__((ext_vector_type(4))) float f32x4;

constexpr int kB = 8, kN = 8192, kE = 65536;
constexpr int kBN = kB * kN;    // 65536 nodes total
constexpr int kBE = kB * kE;    // 524288 edges total
constexpr int kDN = 64, kDE = 64, kIU = 128;

constexpr int XS = 200;  // X row stride in bf16 (192 + 8 pad)
constexpr int HS = 136;  // H row stride (128 + 8)
constexpr int ES = 72;   // E row stride (64 + 8)

// LDS-only barrier: leaves global loads/stores outstanding across the barrier.
__device__ __forceinline__ void lds_barrier() {
    asm volatile("s_waitcnt lgkmcnt(0)\n\ts_barrier" ::: "memory");
}

// ---------------------------------------------------------------------------
// CSR path kernels
// ---------------------------------------------------------------------------

// Histogram of receivers (int atomics) + float casts of s_flat/r_flat outputs.
__global__ __launch_bounds__(256)
void hist_kernel(const int* __restrict__ senders,
                 const int* __restrict__ receivers,
                 int* __restrict__ cnt,
                 float* __restrict__ out_sf,
                 float* __restrict__ out_rf)
{
    const int t = blockIdx.x * blockDim.x + threadIdx.x;   // < kBE/4
    const int b = t >> 14;                                 // (4t)>>16
    int4 s = ((const int4*)senders)[t];
    int4 r = ((const int4*)receivers)[t];
    ((float4*)out_sf)[t] = (float4){(float)s.x, (float)s.y, (float)s.z, (float)s.w};
    ((float4*)out_rf)[t] = (float4){(float)r.x, (float)r.y, (float)r.z, (float)r.w};
    const int base = b << 13;
    if (r.x >= 0) atomicAdd(&cnt[r.x + base], 1);
    if (r.y >= 0) atomicAdd(&cnt[r.y + base], 1);
    if (r.z >= 0) atomicAdd(&cnt[r.z + base], 1);
    if (r.w >= 0) atomicAdd(&cnt[r.w + base], 1);
}

// Exclusive prefix scan of cnt[65536] -> starts, cursor (single block).
__global__ __launch_bounds__(1024)
void scan_kernel(const int* __restrict__ cnt,
                 int* __restrict__ starts,
                 int* __restrict__ cursor)
{
    __shared__ int part[1024];
    const int t = threadIdx.x;
    const int base = t * 64;
    int local[64];
    int tot = 0;
    const int4* c4 = (const int4*)(cnt + base);
#pragma unroll
    for (int i = 0; i < 16; ++i) {
        int4 v = c4[i];
        local[4*i] = v.x; local[4*i+1] = v.y; local[4*i+2] = v.z; local[4*i+3] = v.w;
        tot += v.x + v.y + v.z + v.w;
    }
    part[t] = tot;
    __syncthreads();
    for (int off = 1; off < 1024; off <<= 1) {
        int v = (t >= off) ? part[t - off] : 0;
        __syncthreads();
        part[t] += v;
        __syncthreads();
    }
    int run = part[t] - tot;   // exclusive offset for this thread's chunk
#pragma unroll
    for (int i = 0; i < 16; ++i) {
        int4 o;
        o.x = run; run += local[4*i];
        o.y = run; run += local[4*i+1];
        o.z = run; run += local[4*i+2];
        o.w = run; run += local[4*i+3];
        ((int4*)(starts + base))[i] = o;
        ((int4*)(cursor + base))[i] = o;
    }
}

// Scatter edge ids into CSR slots.
__global__ __launch_bounds__(256)
void scatter_kernel(const int* __restrict__ receivers,
                    int* __restrict__ cursor,
                    int* __restrict__ eids)
{
    const int e = blockIdx.x * blockDim.x + threadIdx.x;   // < kBE
    const int r = receivers[e];
    if (r >= 0) {
        const int pos = atomicAdd(&cursor[r + ((e >> 16) << 13)], 1);
        eids[pos] = e;
    }
}

// Per-node gather mean: one wave per node, lane = column.
__global__ __launch_bounds__(256)
void node_gather_kernel(const __bf16* __restrict__ enew,
                        const int* __restrict__ cnt,
                        const int* __restrict__ starts,
                        float* __restrict__ out_nodes)
{
    const int n = blockIdx.x * 4 + (threadIdx.x >> 6);
    const int lane = threadIdx.x & 63;
    const int deg = cnt[n];
    const int st  = starts[n];
    float acc0 = 0.f, acc1 = 0.f;
    int i = st;
    const int end = st + deg;
    for (; i + 1 < end; i += 2) {
        const int e0 = starts == nullptr ? 0 : 0;  // (no-op; keep compiler honest)
        const int a = ((const int*)0 == nullptr) ? 0 : 0;
        (void)e0; (void)a;
        int id0, id1;
        id0 = *(const int*)&((const int*)starts)[0];  // placeholder removed below
        (void)id0; (void)id1;
        break;
    }
    // (clean loop)
    acc0 = 0.f; acc1 = 0.f;
    i = st;
    const int* eids = starts + kBN;   // eids region sits right after starts+cursor; see launch
    for (; i + 1 < end; i += 2) {
        const int e0 = eids[i], e1 = eids[i + 1];
        acc0 += (float)enew[(size_t)e0 * kDN + lane];
        acc1 += (float)enew[(size_t)e1 * kDN + lane];
    }
    if (i < end) {
        const int e0 = eids[i];
        acc0 += (float)enew[(size_t)e0 * kDN + lane];
    }
    const float s = acc0 + acc1;
    out_nodes[(size_t)n * kDN + lane] = (deg > 0) ? s / (float)deg : 0.f;
}

// Fused edge MLP, CSR variant: no atomics; e_new stored bf16 to ws.
__global__ __launch_bounds__(256, 3)
void edge_mlp_csr(const float* __restrict__ nodes,
                  const float* __restrict__ edges,
                  const int* __restrict__ senders,
                  const int* __restrict__ receivers,
                  const float* __restrict__ W_in,
                  const float* __restrict__ b_in,
                  const float* __restrict__ W_out,
                  const float* __restrict__ b_out,
                  const float* __restrict__ W_edge,
                  const float* __restrict__ b_edge,
                  float* __restrict__ edges_out,
                  __bf16* __restrict__ enew_ws)
{
    __shared__ alignas(16) __bf16 Xs_[64 * XS];
    __shared__ alignas(16) __bf16 Hs_[64 * HS];
    __shared__ alignas(16) __bf16 Es_[64 * ES];

    const int tid  = threadIdx.x;
    const int lane = tid & 63;
    const int wave = tid >> 6;
    const int c16  = lane & 15;
    const int q    = lane >> 4;

    bf16x8 winf[6][2];
#pragma unroll
    for (int kk = 0; kk < 6; ++kk)
#pragma unroll
        for (int nt = 0; nt < 2; ++nt)
#pragma unroll
            for (int j = 0; j < 8; ++j)
                winf[kk][nt][j] =
                    (__bf16)W_in[(kk * 32 + q * 8 + j) * kIU + wave * 32 + nt * 16 + c16];

    bf16x8 woutf[4];
#pragma unroll
    for (int kk = 0; kk < 4; ++kk)
#pragma unroll
        for (int j = 0; j < 8; ++j)
            woutf[kk][j] =
                (__bf16)W_out[(kk * 32 + q * 8 + j) * kDN + wave * 16 + c16];

    bf16x8 wedgef[2];
#pragma unroll
    for (int kk = 0; kk < 2; ++kk)
#pragma unroll
        for (int j = 0; j < 8; ++j)
            wedgef[kk][j] =
                (__bf16)W_edge[(kk * 32 + q * 8 + j) * kDE + wave * 16 + c16];

    const float bin0 = b_in[wave * 32 + c16];
    const float bin1 = b_in[wave * 32 + 16 + c16];
    const float bo   = b_out[wave * 16 + c16];
    const float beg  = b_edge[wave * 16 + c16];

    const int row = tid >> 2;
    const int qt  = tid & 3;

    const int ntiles = kBE / 64;
    const int stride = gridDim.x;

    int t = blockIdx.x;
    int rN, sN;
    float4 G[12];
    {
        const int g = t * 64 + row;
        const int r = receivers[g];
        const int s = senders[g];
        const int b  = g >> 16;
        const int rg = (r < 0) ? (kBN - 1) : r + (b << 13);
        const int sg = (s < 0) ? (kBN - 1) : s + (b << 13);
        const float4* nrec = (const float4*)nodes + (size_t)rg * 16;
        const float4* ez   = (const float4*)edges + (size_t)g * 16;
        const float4* nsnd = (const float4*)nodes + (size_t)sg * 16;
#pragma unroll
        for (int i = 0; i < 4; ++i) {
            G[i]     = nrec[qt + 4 * i];
            G[4 + i] = ez  [qt + 4 * i];
            G[8 + i] = nsnd[qt + 4 * i];
        }
        const int t1 = (t + stride < ntiles) ? (t + stride) : t;
        const int g1 = t1 * 64 + row;
        rN = receivers[g1];
        sN = senders[g1];
    }

    for (; t < ntiles; t += stride) {
        const int g0 = t * 64;

        // ---- stage X (bank-spread column map) ----
        {
            __bf16* xr = &Xs_[row * XS];
#pragma unroll
            for (int i = 0; i < 4; ++i) {
                const int c = 4 * qt + 16 * i;
                float4 a = G[i], e = G[4 + i], s = G[8 + i];
                *(bf16x4*)&xr[c] =
                    (bf16x4){(__bf16)a.x, (__bf16)a.y, (__bf16)a.z, (__bf16)a.w};
                *(bf16x4*)&xr[64 + c] =
                    (bf16x4){(__bf16)e.x, (__bf16)e.y, (__bf16)e.z, (__bf16)e.w};
                *(bf16x4*)&xr[128 + c] =
                    (bf16x4){(__bf16)s.x, (__bf16)s.y, (__bf16)s.z, (__bf16)s.w};
            }
        }
        lds_barrier();   // B1: X ready

        // ---- prefetch gathers for t+stride, idx for t+2*stride ----
        {
            const int tn = (t + stride < ntiles) ? (t + stride) : t;
            const int gn = tn * 64 + row;
            const int b  = gn >> 16;
            const int rg = (rN < 0) ? (kBN - 1) : rN + (b << 13);
            const int sg = (sN < 0) ? (kBN - 1) : sN + (b << 13);
            const float4* nrec = (const float4*)nodes + (size_t)rg * 16;
            const float4* ez   = (const float4*)edges + (size_t)gn * 16;
            const float4* nsnd = (const float4*)nodes + (size_t)sg * 16;
#pragma unroll
            for (int i = 0; i < 4; ++i) {
                G[i]     = nrec[qt + 4 * i];
                G[4 + i] = ez  [qt + 4 * i];
                G[8 + i] = nsnd[qt + 4 * i];
            }
            const int t2 = (t + 2 * stride < ntiles) ? (t + 2 * stride) : tn;
            const int g2 = t2 * 64 + row;
            rN = receivers[g2];
            sN = senders[g2];
        }

        // ---- layer 1 ----
#pragma unroll
        for (int m = 0; m < 4; ++m) {
            const __bf16* ar = &Xs_[(m * 16 + c16) * XS + q * 8];
            bf16x8 a[6];
#pragma unroll
            for (int kk = 0; kk < 6; ++kk) a[kk] = *(const bf16x8*)(ar + kk * 32);
            f32x4 acc0 = (f32x4){0.f, 0.f, 0.f, 0.f};
            f32x4 acc1 = (f32x4){0.f, 0.f, 0.f, 0.f};
#pragma unroll
            for (int kk = 0; kk < 6; ++kk)
                acc0 = __builtin_amdgcn_mfma_f32_16x16x32_bf16(a[kk], winf[kk][0], acc0, 0, 0, 0);
#pragma unroll
            for (int kk = 0; kk < 6; ++kk)
                acc1 = __builtin_amdgcn_mfma_f32_16x16x32_bf16(a[kk], winf[kk][1], acc1, 0, 0, 0);
#pragma unroll
            for (int r = 0; r < 4; ++r) {
                __bf16* hr = &Hs_[(m * 16 + q * 4 + r) * HS + wave * 32];
                hr[c16]      = (__bf16)fmaxf(acc0[r] + bin0, 0.f);
                hr[16 + c16] = (__bf16)fmaxf(acc1[r] + bin1, 0.f);
            }
        }
        lds_barrier();   // B2: H ready

        // ---- layer 2 -> e_new ----
#pragma unroll
        for (int m = 0; m < 4; ++m) {
            const __bf16* ar = &Hs_[(m * 16 + c16) * HS + q * 8];
            bf16x8 a[4];
#pragma unroll
            for (int kk = 0; kk < 4; ++kk) a[kk] = *(const bf16x8*)(ar + kk * 32);
            f32x4 acc = (f32x4){0.f, 0.f, 0.f, 0.f};
#pragma unroll
            for (int kk = 0; kk < 4; ++kk)
                acc = __builtin_amdgcn_mfma_f32_16x16x32_bf16(a[kk], woutf[kk], acc, 0, 0, 0);
#pragma unroll
            for (int r = 0; r < 4; ++r)
                Es_[(m * 16 + q * 4 + r) * ES + wave * 16 + c16] =
                    (__bf16)fmaxf(acc[r] + bo, 0.f);
        }
        lds_barrier();   // B3: E ready

        // ---- layer 3 -> edges_out ----
#pragma unroll
        for (int m = 0; m < 4; ++m) {
            const __bf16* ar = &Es_[(m * 16 + c16) * ES + q * 8];
            bf16x8 a0 = *(const bf16x8*)ar;
            bf16x8 a1 = *(const bf16x8*)(ar + 32);
            f32x4 acc = (f32x4){0.f, 0.f, 0.f, 0.f};
            acc = __builtin_amdgcn_mfma_f32_16x16x32_bf16(a0, wedgef[0], acc, 0, 0, 0);
            acc = __builtin_amdgcn_mfma_f32_16x16x32_bf16(a1, wedgef[1], acc, 0, 0, 0);
#pragma unroll
            for (int r = 0; r < 4; ++r)
                edges_out[(size_t)(g0 + m * 16 + q * 4 + r) * kDE + wave * 16 + c16] =
                    fmaxf(acc[r] + beg, 0.f);
        }

        // ---- store e_new tile to ws, vectorized (two 16B stores/thread) ----
        {
            const int c = qt * 16;
            bf16x8 v0 = *(const bf16x8*)&Es_[row * ES + c];
            bf16x8 v1 = *(const bf16x8*)&Es_[row * ES + c + 8];
            __bf16* dst = enew_ws + (size_t)(g0 + row) * kDN + c;
            *(bf16x8*)dst       = v0;
            *(bf16x8*)(dst + 8) = v1;
        }
    }
}

// ---------------------------------------------------------------------------
// Fallback path (R2 pipeline) if ws_size is too small for CSR
// ---------------------------------------------------------------------------
__global__ __launch_bounds__(256, 3)
void edge_mlp_atomic(const float* __restrict__ nodes,
                     const float* __restrict__ edges,
                     const int* __restrict__ senders,
                     const int* __restrict__ receivers,
                     const float* __restrict__ W_in,
                     const float* __restrict__ b_in,
                     const float* __restrict__ W_out,
                     const float* __restrict__ b_out,
                     const float* __restrict__ W_edge,
                     const float* __restrict__ b_edge,
                     float* __restrict__ edges_out,
                     float* __restrict__ out_sf,
                     float* __restrict__ out_rf,
                     float* __restrict__ sums,
                     float* __restrict__ counts)
{
    __shared__ alignas(16) __bf16 Xs_[64 * XS];
    __shared__ alignas(16) __bf16 Hs_[64 * HS];
    __shared__ alignas(16) __bf16 Es_[64 * ES];
    __shared__ int rsS[2][64];

    const int tid  = threadIdx.x;
    const int lane = tid & 63;
    const int wave = tid >> 6;
    const int c16  = lane & 15;
    const int q    = lane >> 4;

    bf16x8 winf[6][2];
#pragma unroll
    for (int kk = 0; kk < 6; ++kk)
#pragma unroll
        for (int nt = 0; nt < 2; ++nt)
#pragma unroll
            for (int j = 0; j < 8; ++j)
                winf[kk][nt][j] =
                    (__bf16)W_in[(kk * 32 + q * 8 + j) * kIU + wave * 32 + nt * 16 + c16];
    bf16x8 woutf[4];
#pragma unroll
    for (int kk = 0; kk < 4; ++kk)
#pragma unroll
        for (int j = 0; j < 8; ++j)
            woutf[kk][j] = (__bf16)W_out[(kk * 32 + q * 8 + j) * kDN + wave * 16 + c16];
    bf16x8 wedgef[2];
#pragma unroll
    for (int kk = 0; kk < 2; ++kk)
#pragma unroll
        for (int j = 0; j < 8; ++j)
            wedgef[kk][j] = (__bf16)W_edge[(kk * 32 + q * 8 + j) * kDE + wave * 16 + c16];

    const float bin0 = b_in[wave * 32 + c16];
    const float bin1 = b_in[wave * 32 + 16 + c16];
    const float bo   = b_out[wave * 16 + c16];
    const float beg  = b_edge[wave * 16 + c16];

    const int row = tid >> 2;
    const int qt  = tid & 3;
    const int ntiles = kBE / 64;
    const int stride = gridDim.x;

    int t = blockIdx.x;
    int rV, sV, rN, sN;
    float4 G[12];
    {
        const int g = t * 64 + row;
        rV = receivers[g]; sV = senders[g];
        const int b  = g >> 16;
        const int rg = (rV < 0) ? (kBN - 1) : rV + (b << 13);
        const int sg = (sV < 0) ? (kBN - 1) : sV + (b << 13);
        const float4* nrec = (const float4*)nodes + (size_t)rg * 16;
        const float4* ez   = (const float4*)edges + (size_t)g * 16;
        const float4* nsnd = (const float4*)nodes + (size_t)sg * 16;
#pragma unroll
        for (int i = 0; i < 4; ++i) {
            G[i] = nrec[qt + 4 * i]; G[4 + i] = ez[qt + 4 * i]; G[8 + i] = nsnd[qt + 4 * i];
        }
        const int t1 = (t + stride < ntiles) ? (t + stride) : t;
        const int g1 = t1 * 64 + row;
        rN = receivers[g1]; sN = senders[g1];
    }

    int buf = 0;
    for (; t < ntiles; t += stride) {
        const int g0 = t * 64;
        {
            const int b  = (g0 + row) >> 16;
            const int rs = (rV < 0) ? -1 : rV + (b << 13);
            if (qt == 0) {
                rsS[buf][row] = rs;
                const int g = g0 + row;
                out_sf[g] = (float)sV;
                out_rf[g] = (float)rV;
                if (rs >= 0) atomicAdd(&counts[rs], 1.0f);
            }
            __bf16* xr = &Xs_[row * XS];
#pragma unroll
            for (int i = 0; i < 4; ++i) {
                const int c = 4 * qt + 16 * i;
                float4 a = G[i], e = G[4 + i], s = G[8 + i];
                *(bf16x4*)&xr[c]       = (bf16x4){(__bf16)a.x,(__bf16)a.y,(__bf16)a.z,(__bf16)a.w};
                *(bf16x4*)&xr[64 + c]  = (bf16x4){(__bf16)e.x,(__bf16)e.y,(__bf16)e.z,(__bf16)e.w};
                *(bf16x4*)&xr[128 + c] = (bf16x4){(__bf16)s.x,(__bf16)s.y,(__bf16)s.z,(__bf16)s.w};
            }
        }
        lds_barrier();
        {
            const int rG = rN, sG = sN;
            const int tn = (t + stride < ntiles) ? (t + stride) : t;
            const int gn = tn * 64 + row;
            const int b  = gn >> 16;
            const int rg = (rG < 0) ? (kBN - 1) : rG + (b << 13);
            const int sg = (sG < 0) ? (kBN - 1) : sG + (b << 13);
            const float4* nrec = (const float4*)nodes + (size_t)rg * 16;
            const float4* ez   = (const float4*)edges + (size_t)gn * 16;
            const float4* nsnd = (const float4*)nodes + (size_t)sg * 16;
#pragma unroll
            for (int i = 0; i < 4; ++i) {
                G[i] = nrec[qt + 4 * i]; G[4 + i] = ez[qt + 4 * i]; G[8 + i] = nsnd[qt + 4 * i];
            }
            const int t2 = (t + 2 * stride < ntiles) ? (t + 2 * stride) : tn;
            const int g2 = t2 * 64 + row;
            rN = receivers[g2]; sN = senders[g2];
            rV = rG; sV = sG;
        }
#pragma unroll
        for (int m = 0; m < 4; ++m) {
            const __bf16* ar = &Xs_[(m * 16 + c16) * XS + q * 8];
            bf16x8 a[6];
#pragma unroll
            for (int kk = 0; kk < 6; ++kk) a[kk] = *(const bf16x8*)(ar + kk * 32);
            f32x4 acc0 = (f32x4){0.f,0.f,0.f,0.f}, acc1 = (f32x4){0.f,0.f,0.f,0.f};
#pragma unroll
            for (int kk = 0; kk < 6; ++kk)
                acc0 = __builtin_amdgcn_mfma_f32_16x16x32_bf16(a[kk], winf[kk][0], acc0, 0, 0, 0);
#pragma unroll
            for (int kk = 0; kk < 6; ++kk)
                acc1 = __builtin_amdgcn_mfma_f32_16x16x32_bf16(a[kk], winf[kk][1], acc1, 0, 0, 0);
#pragma unroll
            for (int r = 0; r < 4; ++r) {
                __bf16* hr = &Hs_[(m * 16 + q * 4 + r) * HS + wave * 32];
                hr[c16]      = (__bf16)fmaxf(acc0[r] + bin0, 0.f);
                hr[16 + c16] = (__bf16)fmaxf(acc1[r] + bin1, 0.f);
            }
        }
        lds_barrier();
#pragma unroll
        for (int m = 0; m < 4; ++m) {
            const __bf16* ar = &Hs_[(m * 16 + c16) * HS + q * 8];
            bf16x8 a[4];
#pragma unroll
            for (int kk = 0; kk < 4; ++kk) a[kk] = *(const bf16x8*)(ar + kk * 32);
            f32x4 acc = (f32x4){0.f,0.f,0.f,0.f};
#pragma unroll
            for (int kk = 0; kk < 4; ++kk)
                acc = __builtin_amdgcn_mfma_f32_16x16x32_bf16(a[kk], woutf[kk], acc, 0, 0, 0);
#pragma unroll
            for (int r = 0; r < 4; ++r)
                Es_[(m * 16 + q * 4 + r) * ES + wave * 16 + c16] = (__bf16)fmaxf(acc[r] + bo, 0.f);
        }
        lds_barrier();
#pragma unroll
        for (int m = 0; m < 4; ++m) {
            const __bf16* ar = &Es_[(m * 16 + c16) * ES + q * 8];
            bf16x8 a0 = *(const bf16x8*)ar;
            bf16x8 a1 = *(const bf16x8*)(ar + 32);
            f32x4 acc = (f32x4){0.f,0.f,0.f,0.f};
            acc = __builtin_amdgcn_mfma_f32_16x16x32_bf16(a0, wedgef[0], acc, 0, 0, 0);
            acc = __builtin_amdgcn_mfma_f32_16x16x32_bf16(a1, wedgef[1], acc, 0, 0, 0);
#pragma unroll
            for (int r = 0; r < 4; ++r)
                edges_out[(size_t)(g0 + m * 16 + q * 4 + r) * kDE + wave * 16 + c16] =
                    fmaxf(acc[r] + beg, 0.f);
        }
#pragma unroll
        for (int i = 0; i < 16; ++i) {
            const int rr = i * 4 + wave;
            const int rs = rsS[buf][rr];
            if (rs >= 0) {
                float v = (float)Es_[rr * ES + lane];
                atomicAdd(&sums[(size_t)rs * kDN + lane], v);
            }
        }
        buf ^= 1;
    }
}

__global__ __launch_bounds__(256)
void finalize_kernel(const float* __restrict__ sums,
                     const float* __restrict__ counts,
                     float* __restrict__ out)
{
    const int t = blockIdx.x * blockDim.x + threadIdx.x;
    float4 s = ((const float4*)sums)[t];
    const float c = counts[t >> 4];
    float4 o;
    if (c > 0.f) {
        const float inv = 1.f / c;
        o.x = s.x*inv; o.y = s.y*inv; o.z = s.z*inv; o.w = s.w*inv;
    } else { o.x = o.y = o.z = o.w = 0.f; }
    ((float4*)out)[t] = o;
}

// ---------------------------------------------------------------------------
extern "C" void kernel_launch(void* const* d_in, const int* in_sizes, int n_in,
                              void* d_out, int out_size, void* d_ws, size_t ws_size,
                              hipStream_t stream) {
    const float* nodes     = (const float*)d_in[0];
    const float* edges     = (const float*)d_in[1];
    const int*   senders   = (const int*)d_in[2];
    const int*   receivers = (const int*)d_in[3];
    const float* W_in      = (const float*)d_in[4];
    const float* b_in      = (const float*)d_in[5];
    const float* W_out     = (const float*)d_in[6];
    const float* b_out     = (const float*)d_in[7];
    const float* W_edge    = (const float*)d_in[8];
    const float* b_edge    = (const float*)d_in[9];

    float* out       = (float*)d_out;
    float* edges_out = out + (size_t)kBN * kDN;
    float* out_sf    = edges_out + (size_t)kBE * kDE;
    float* out_rf    = out_sf + kBE;

    // ws layout (CSR): enew bf16 [64 MiB] | cnt [256K] | starts [256K] |
    //                  cursor [256K] | eids [2 MiB]
    const size_t enew_bytes = (size_t)kBE * kDN * 2;        // 67108864
    const size_t need = enew_bytes + 3u * kBN * 4 + (size_t)kBE * 4;

    if (ws_size >= need) {
        __bf16* enew  = (__bf16*)d_ws;
        int* cnt      = (int*)((char*)d_ws + enew_bytes);
        int* starts   = cnt + kBN;
        int* cursor   = starts + kBN;
        int* eids     = cursor + kBN;   // == starts + kBN + kBN (gather kernel relies on this)

        hipMemsetAsync(cnt, 0, (size_t)kBN * 4, stream);

        hist_kernel<<<kBE / 4 / 256, 256, 0, stream>>>(senders, receivers, cnt, out_sf, out_rf);
        scan_kernel<<<1, 1024, 0, stream>>>(cnt, starts, cursor);
        scatter_kernel<<<kBE / 256, 256, 0, stream>>>(receivers, cursor, eids);
        edge_mlp_csr<<<2048, 256, 0, stream>>>(
            nodes, edges, senders, receivers,
            W_in, b_in, W_out, b_out, W_edge, b_edge,
            edges_out, enew);
        node_gather_kernel<<<kBN / 4, 256, 0, stream>>>(enew, cnt, starts, out);
    } else {
        float* sums   = (float*)d_ws;
        float* counts = sums + (size_t)kBN * kDN;
        hipMemsetAsync(d_ws, 0, (size_t)(kBN * kDN + kBN) * sizeof(float), stream);
        edge_mlp_atomic<<<2048, 256, 0, stream>>>(
            nodes, edges, senders, receivers,
            W_in, b_in, W_out, b_out, W_edge, b_edge,
            edges_out, out_sf, out_rf, sums, counts);
        finalize_kernel<<<kBN * kDN / 4 / 256, 256, 0, stream>>>(sums, counts, out);
    }
}

// Round 4
// 373.501 us; speedup vs baseline: 1.2043x; 1.2043x over previous
//
#include <hip/hip_runtime.h>

typedef __attribute__((ext_vector_type(8))) __bf16 bf16x8;
typedef __attribute__((ext_vector_type(4))) __bf16 bf16x4;
typedef __attribute__((ext_vector_type(4))) float f32x4;

constexpr int kB = 8, kN = 8192, kE = 65536;
constexpr int kBN = kB * kN;    // 65536 nodes total
constexpr int kBE = kB * kE;    // 524288 edges total
constexpr int kDN = 64, kDE = 64, kIU = 128;

constexpr int XS = 200;  // X row stride in bf16 (192 + 8 pad)
constexpr int HS = 136;  // H row stride (128 + 8)
constexpr int ES = 72;   // E row stride (64 + 8)

// LDS-only barrier: leaves global loads/stores/atomics outstanding across it.
__device__ __forceinline__ void lds_barrier() {
    asm volatile("s_waitcnt lgkmcnt(0)\n\ts_barrier" ::: "memory");
}

// Packed bf16x2 atomic add (device scope via sc1). addr first, data second.
__device__ __forceinline__ void atomic_pk_add_bf16(__bf16* p, uint32_t pk) {
    const unsigned long long a64 = (unsigned long long)p;
    asm volatile("global_atomic_pk_add_bf16 %0, %1, off sc1"
                 :: "v"(a64), "v"(pk) : "memory");
}

// ---------------------------------------------------------------------------
// Fused edge MLP: gather -> L1 -> L2 (e_new) -> L3 (edges_out)
//   e_new scattered into bf16 sums table via packed-bf16 atomics (2 cols/op).
//   counts via fp32 atomics (1/edge). sf/rf float casts fused here too.
// ---------------------------------------------------------------------------
__global__ __launch_bounds__(256, 3)
void edge_mlp_pk(const float* __restrict__ nodes,
                 const float* __restrict__ edges,
                 const int* __restrict__ senders,
                 const int* __restrict__ receivers,
                 const float* __restrict__ W_in,
                 const float* __restrict__ b_in,
                 const float* __restrict__ W_out,
                 const float* __restrict__ b_out,
                 const float* __restrict__ W_edge,
                 const float* __restrict__ b_edge,
                 float* __restrict__ edges_out,
                 float* __restrict__ out_sf,
                 float* __restrict__ out_rf,
                 __bf16* __restrict__ sums,     // [kBN][64] bf16
                 float* __restrict__ counts)    // [kBN] fp32
{
    __shared__ alignas(16) __bf16 Xs_[64 * XS];
    __shared__ alignas(16) __bf16 Hs_[64 * HS];
    __shared__ alignas(16) __bf16 Es_[64 * ES];
    __shared__ int rsS[2][64];

    const int tid  = threadIdx.x;
    const int lane = tid & 63;
    const int wave = tid >> 6;
    const int c16  = lane & 15;
    const int q    = lane >> 4;

    // ---- weight B-fragments in registers (loaded once per block) ----
    bf16x8 winf[6][2];
#pragma unroll
    for (int kk = 0; kk < 6; ++kk)
#pragma unroll
        for (int nt = 0; nt < 2; ++nt)
#pragma unroll
            for (int j = 0; j < 8; ++j)
                winf[kk][nt][j] =
                    (__bf16)W_in[(kk * 32 + q * 8 + j) * kIU + wave * 32 + nt * 16 + c16];
    bf16x8 woutf[4];
#pragma unroll
    for (int kk = 0; kk < 4; ++kk)
#pragma unroll
        for (int j = 0; j < 8; ++j)
            woutf[kk][j] = (__bf16)W_out[(kk * 32 + q * 8 + j) * kDN + wave * 16 + c16];
    bf16x8 wedgef[2];
#pragma unroll
    for (int kk = 0; kk < 2; ++kk)
#pragma unroll
        for (int j = 0; j < 8; ++j)
            wedgef[kk][j] = (__bf16)W_edge[(kk * 32 + q * 8 + j) * kDE + wave * 16 + c16];

    const float bin0 = b_in[wave * 32 + c16];
    const float bin1 = b_in[wave * 32 + 16 + c16];
    const float bo   = b_out[wave * 16 + c16];
    const float beg  = b_edge[wave * 16 + c16];

    const int row = tid >> 2;   // edge row within tile
    const int qt  = tid & 3;    // column-quarter owner
    const int ntiles = kBE / 64;
    const int stride = gridDim.x;

    int t = blockIdx.x;
    int rV, sV, rN, sN;
    float4 G[12];
    {
        const int g = t * 64 + row;
        rV = receivers[g]; sV = senders[g];
        const int b  = g >> 16;
        const int rg = (rV < 0) ? (kBN - 1) : rV + (b << 13);
        const int sg = (sV < 0) ? (kBN - 1) : sV + (b << 13);
        const float4* nrec = (const float4*)nodes + (size_t)rg * 16;
        const float4* ez   = (const float4*)edges + (size_t)g * 16;
        const float4* nsnd = (const float4*)nodes + (size_t)sg * 16;
#pragma unroll
        for (int i = 0; i < 4; ++i) {
            G[i] = nrec[qt + 4 * i]; G[4 + i] = ez[qt + 4 * i]; G[8 + i] = nsnd[qt + 4 * i];
        }
        const int t1 = (t + stride < ntiles) ? (t + stride) : t;
        const int g1 = t1 * 64 + row;
        rN = receivers[g1]; sN = senders[g1];
    }

    int buf = 0;
    for (; t < ntiles; t += stride) {
        const int g0 = t * 64;

        // ---- stage X + per-edge side effects ----
        {
            const int b  = (g0 + row) >> 16;
            const int rs = (rV < 0) ? -1 : rV + (b << 13);
            if (qt == 0) {
                rsS[buf][row] = rs;
                const int g = g0 + row;
                out_sf[g] = (float)sV;
                out_rf[g] = (float)rV;
                if (rs >= 0) atomicAdd(&counts[rs], 1.0f);
            }
            __bf16* xr = &Xs_[row * XS];
#pragma unroll
            for (int i = 0; i < 4; ++i) {
                const int c = 4 * qt + 16 * i;   // bank-spread: 2-way max (free)
                float4 a = G[i], e = G[4 + i], s = G[8 + i];
                *(bf16x4*)&xr[c]       = (bf16x4){(__bf16)a.x,(__bf16)a.y,(__bf16)a.z,(__bf16)a.w};
                *(bf16x4*)&xr[64 + c]  = (bf16x4){(__bf16)e.x,(__bf16)e.y,(__bf16)e.z,(__bf16)e.w};
                *(bf16x4*)&xr[128 + c] = (bf16x4){(__bf16)s.x,(__bf16)s.y,(__bf16)s.z,(__bf16)s.w};
            }
        }
        lds_barrier();   // B1: X ready

        // ---- prefetch gathers for t+stride, indices for t+2*stride ----
        {
            const int rG = rN, sG = sN;
            const int tn = (t + stride < ntiles) ? (t + stride) : t;
            const int gn = tn * 64 + row;
            const int b  = gn >> 16;
            const int rg = (rG < 0) ? (kBN - 1) : rG + (b << 13);
            const int sg = (sG < 0) ? (kBN - 1) : sG + (b << 13);
            const float4* nrec = (const float4*)nodes + (size_t)rg * 16;
            const float4* ez   = (const float4*)edges + (size_t)gn * 16;
            const float4* nsnd = (const float4*)nodes + (size_t)sg * 16;
#pragma unroll
            for (int i = 0; i < 4; ++i) {
                G[i] = nrec[qt + 4 * i]; G[4 + i] = ez[qt + 4 * i]; G[8 + i] = nsnd[qt + 4 * i];
            }
            const int t2 = (t + 2 * stride < ntiles) ? (t + 2 * stride) : tn;
            const int g2 = t2 * 64 + row;
            rN = receivers[g2]; sN = senders[g2];
            rV = rG; sV = sG;
        }

        // ---- layer 1: [64x192]@[192x128] -> H ----
#pragma unroll
        for (int m = 0; m < 4; ++m) {
            const __bf16* ar = &Xs_[(m * 16 + c16) * XS + q * 8];
            bf16x8 a[6];
#pragma unroll
            for (int kk = 0; kk < 6; ++kk) a[kk] = *(const bf16x8*)(ar + kk * 32);
            f32x4 acc0 = (f32x4){0.f,0.f,0.f,0.f}, acc1 = (f32x4){0.f,0.f,0.f,0.f};
#pragma unroll
            for (int kk = 0; kk < 6; ++kk)
                acc0 = __builtin_amdgcn_mfma_f32_16x16x32_bf16(a[kk], winf[kk][0], acc0, 0, 0, 0);
#pragma unroll
            for (int kk = 0; kk < 6; ++kk)
                acc1 = __builtin_amdgcn_mfma_f32_16x16x32_bf16(a[kk], winf[kk][1], acc1, 0, 0, 0);
#pragma unroll
            for (int r = 0; r < 4; ++r) {
                __bf16* hr = &Hs_[(m * 16 + q * 4 + r) * HS + wave * 32];
                hr[c16]      = (__bf16)fmaxf(acc0[r] + bin0, 0.f);
                hr[16 + c16] = (__bf16)fmaxf(acc1[r] + bin1, 0.f);
            }
        }
        lds_barrier();   // B2: H ready

        // ---- layer 2: [64x128]@[128x64] -> E (e_new) ----
#pragma unroll
        for (int m = 0; m < 4; ++m) {
            const __bf16* ar = &Hs_[(m * 16 + c16) * HS + q * 8];
            bf16x8 a[4];
#pragma unroll
            for (int kk = 0; kk < 4; ++kk) a[kk] = *(const bf16x8*)(ar + kk * 32);
            f32x4 acc = (f32x4){0.f,0.f,0.f,0.f};
#pragma unroll
            for (int kk = 0; kk < 4; ++kk)
                acc = __builtin_amdgcn_mfma_f32_16x16x32_bf16(a[kk], woutf[kk], acc, 0, 0, 0);
#pragma unroll
            for (int r = 0; r < 4; ++r)
                Es_[(m * 16 + q * 4 + r) * ES + wave * 16 + c16] = (__bf16)fmaxf(acc[r] + bo, 0.f);
        }
        lds_barrier();   // B3: E ready

        // ---- layer 3: [64x64]@[64x64] -> edges_out ----
#pragma unroll
        for (int m = 0; m < 4; ++m) {
            const __bf16* ar = &Es_[(m * 16 + c16) * ES + q * 8];
            bf16x8 a0 = *(const bf16x8*)ar;
            bf16x8 a1 = *(const bf16x8*)(ar + 32);
            f32x4 acc = (f32x4){0.f,0.f,0.f,0.f};
            acc = __builtin_amdgcn_mfma_f32_16x16x32_bf16(a0, wedgef[0], acc, 0, 0, 0);
            acc = __builtin_amdgcn_mfma_f32_16x16x32_bf16(a1, wedgef[1], acc, 0, 0, 0);
#pragma unroll
            for (int r = 0; r < 4; ++r)
                edges_out[(size_t)(g0 + m * 16 + q * 4 + r) * kDE + wave * 16 + c16] =
                    fmaxf(acc[r] + beg, 0.f);
        }

        // ---- scatter e_new -> bf16 sums via packed atomics ----
        // wave owns rows [16w,16w+16); 2 rows per step (lane>>5), 32 packed
        // cols (lane&31). Atomic addresses: 128B contiguous per row-half.
        {
            const int half = lane >> 5;
            const int pc   = lane & 31;
#pragma unroll
            for (int i = 0; i < 8; ++i) {
                const int rr = wave * 16 + half * 8 + i;
                const int rs = rsS[buf][rr];
                if (rs >= 0) {
                    const uint32_t pk = *(const uint32_t*)&Es_[rr * ES + pc * 2];
                    atomic_pk_add_bf16(sums + (size_t)rs * kDN + pc * 2, pk);
                }
            }
        }
        buf ^= 1;
    }
}

// nodes_new = counts>0 ? bf16sums/counts : 0  (1 thread = 4 columns)
__global__ __launch_bounds__(256)
void finalize_kernel(const unsigned int* __restrict__ sums_u32,  // 2 bf16 per u32
                     const float* __restrict__ counts,
                     float* __restrict__ out)
{
    const int t = blockIdx.x * blockDim.x + threadIdx.x;   // < kBN*kDN/4
    const unsigned int p0 = sums_u32[t * 2];
    const unsigned int p1 = sums_u32[t * 2 + 1];
    const float c = counts[t >> 4];
    float4 o;
    if (c > 0.f) {
        const float inv = 1.f / c;
        union { unsigned int u; float f; } v;
        v.u = p0 << 16;            o.x = v.f * inv;
        v.u = p0 & 0xffff0000u;    o.y = v.f * inv;
        v.u = p1 << 16;            o.z = v.f * inv;
        v.u = p1 & 0xffff0000u;    o.w = v.f * inv;
    } else {
        o.x = o.y = o.z = o.w = 0.f;
    }
    ((float4*)out)[t] = o;
}

extern "C" void kernel_launch(void* const* d_in, const int* in_sizes, int n_in,
                              void* d_out, int out_size, void* d_ws, size_t ws_size,
                              hipStream_t stream) {
    const float* nodes     = (const float*)d_in[0];
    const float* edges     = (const float*)d_in[1];
    const int*   senders   = (const int*)d_in[2];
    const int*   receivers = (const int*)d_in[3];
    const float* W_in      = (const float*)d_in[4];
    const float* b_in      = (const float*)d_in[5];
    const float* W_out     = (const float*)d_in[6];
    const float* b_out     = (const float*)d_in[7];
    const float* W_edge    = (const float*)d_in[8];
    const float* b_edge    = (const float*)d_in[9];

    float* out       = (float*)d_out;
    float* edges_out = out + (size_t)kBN * kDN;
    float* out_sf    = edges_out + (size_t)kBE * kDE;
    float* out_rf    = out_sf + kBE;

    // ws: bf16 sums [kBN*64 = 8 MiB] | fp32 counts [256 KiB]  (contiguous)
    __bf16* sums  = (__bf16*)d_ws;
    float* counts = (float*)((char*)d_ws + (size_t)kBN * kDN * 2);

    hipMemsetAsync(d_ws, 0, (size_t)kBN * kDN * 2 + (size_t)kBN * 4, stream);

    edge_mlp_pk<<<2048, 256, 0, stream>>>(
        nodes, edges, senders, receivers,
        W_in, b_in, W_out, b_out, W_edge, b_edge,
        edges_out, out_sf, out_rf, sums, counts);

    finalize_kernel<<<kBN * kDN / 4 / 256, 256, 0, stream>>>(
        (const unsigned int*)sums, counts, out);
}